// Round 16
// baseline (42.909 us; speedup 1.0000x reference)
//
#include <hip/hip_runtime.h>
#include <hip/hip_bf16.h>

// Problem constants
#define NF  200
#define DIN 3
#define NH  15
#define NE  30
#define NB  32768

typedef __attribute__((ext_vector_type(8)))  short short8;
typedef __attribute__((ext_vector_type(16))) float f32x16;

constexpr int FSPLIT = 25;           // feature split across grid.y
constexpr int FPW    = NF / FSPLIT;  // 8 features per block-slice -> 4 pairs
constexpr int PAIRS  = FPW / 2;      // 4
constexpr int BT     = 256;          // threads per block (4 waves)
constexpr int RPB    = 256;          // rows per block (2 tiles of 32 per wave) -> grid.x = 128

// ws layout:
// A1P : [100][64][8 bf16] pair-packed layer-1 A-frag            @ 0       (102400 B)
// W2Q : [200][64][8 bf16] layer-2 W2 fragment (lane=e, k=perm'd h, b2@k15)
//                                                                @ 102400  (204800 B)
// W3F : [200][2][16] f32  W3 in D-fragment order                @ 307200  (25600 B)
constexpr size_t OFF_A1P = 0;
constexpr size_t OFF_W2Q = 102400;
constexpr size_t OFF_W3F = 307200;

__device__ __forceinline__ unsigned f2bfu(float x) {
    __hip_bfloat16 h = __float2bfloat16(x);
    unsigned short u; __builtin_memcpy(&u, &h, 2); return (unsigned)u;
}

// HW packed convert: lo -> D[15:0], hi -> D[31:16], RNE (same as __float2bfloat16)
__device__ __forceinline__ unsigned cvtpk(float lo, float hi) {
    unsigned r;
    asm("v_cvt_pk_bf16_f32 %0, %1, %2" : "=v"(r) : "v"(lo), "v"(hi));
    return r;
}

// VOP3P packed fp32 FMA: d = a*b + c on both halves (2 MACs / instr)
__device__ __forceinline__ float2 pkfma(float2 a, float2 b, float2 c) {
    float2 d;
    asm("v_pk_fma_f32 %0, %1, %2, %3" : "=v"(d) : "v"(a), "v"(b), "v"(c));
    return d;
}

__global__ void nn_init(float* __restrict__ out, const float* __restrict__ b3) {
    int i = blockIdx.x * 256 + threadIdx.x;
    if (i < NB) out[i] = b3[0];
}

__global__ void nn_prep(const float* __restrict__ W1, const float* __restrict__ b1,
                        const float* __restrict__ W2, const float* __restrict__ b2,
                        const float* __restrict__ W3, char* __restrict__ ws) {
    const int f = blockIdx.x;
    const int t = threadIdx.x;      // 64
    const int x = t & 31, hi = t >> 5;
    unsigned short* A1p = (unsigned short*)(ws + OFF_A1P);
    unsigned short* W2q = (unsigned short*)(ws + OFF_W2Q);
    float*          w3f = (float*)(ws + OFF_W3F);

    // ---- W2 fragment (lane=e, k-slots=perm'd h); h==15 slot carries b2 ----
    {
        unsigned short* d = W2q + ((size_t)f * 64 + t) * 8;
#pragma unroll
        for (int j = 0; j < 8; ++j) {
            const int h = (j & 3) + 8 * (j >> 2) + 4 * hi;   // 0..15
            float v = 0.f;
            if (x < NE) v = (h < NH) ? W2[((size_t)f * NH + h) * NE + x]
                                     : b2[f * NE + x];       // h==15
            d[j] = (unsigned short)f2bfu(v);
        }
    }
    // ---- W3 in D-fragment order: W3F[f][hi][r] = W3[e=crow(r,hi)] (e>=30 -> 0)
    if (t < 32) {
        const int hh = t >> 4, r = t & 15;
        const int e = (r & 3) + 8 * (r >> 2) + 4 * hh;
        w3f[(size_t)f * 32 + t] = (e < NE) ? W3[f * NE + e] : 0.f;
    }

    // ---- pair-packed layer-1 A fragment (even f writes pair f/2) ----
    if ((f & 1) == 0) {
        unsigned short* a = A1p + ((size_t)(f >> 1) * 64 + t) * 8;
#pragma unroll
        for (int j = 0; j < 8; ++j) {
            float v = 0.f;
            if (hi == 0) {
                if (x < 16) {                    // feature f, h = x, k0-3
                    if (x < NH) {
                        if (j < 3)       v = W1[((size_t)f * DIN + j) * NH + x];
                        else if (j == 3) v = b1[f * NH + x];
                    }
                } else {                          // feature f+1, h = x-16, k4-7
                    const int h = x - 16;
                    if (h < NH) {
                        if (j >= 4 && j < 7) v = W1[((size_t)(f + 1) * DIN + (j - 4)) * NH + h];
                        else if (j == 7)     v = b1[(f + 1) * NH + h];
                    }
                }
            }
            a[j] = (unsigned short)f2bfu(v);
        }
    }
}

__global__ __launch_bounds__(BT, 4)
void nn_main(const float* __restrict__ y, const char* __restrict__ ws,
             float* __restrict__ out) {
    // LDS-staged per-block weight slice -- 13.3 KB total
    __shared__ __align__(16) short sA1[PAIRS * 512];   //  4096 B = 256 uint4
    __shared__ __align__(16) short sW2[FPW * 512];     //  8192 B = 512 uint4
    __shared__ __align__(16) float sW3f[FPW * 32];     //  1024 B =  64 uint4

    const int t  = threadIdx.x;
    const int w  = t >> 6;
    const int l  = t & 63;
    const int ln = l & 31;
    const int hi = l >> 5;
    const int r0 = blockIdx.x * RPB + w * 32;   // tile 0 rows
    const int r1 = r0 + 128;                    // tile 1 rows
    const int f0 = blockIdx.y * FPW;
    const int p0 = f0 >> 1;

    // y row base pointers for the two tiles (96B-aligned float4 bases)
    const float4* __restrict__ ya4 = reinterpret_cast<const float4*>(
        y + (size_t)(r0 + ln) * (NF * DIN) + (size_t)f0 * DIN);
    const float4* __restrict__ yb4 = reinterpret_cast<const float4*>(
        y + (size_t)(r1 + ln) * (NF * DIN) + (size_t)f0 * DIN);

    // ---- stage weights global -> LDS (coalesced uint4 copies, BT=256) ----
    {
        const uint4* gA = (const uint4*)(ws + OFF_A1P + (size_t)p0 * 1024);
        const uint4* gW = (const uint4*)(ws + OFF_W2Q + (size_t)f0 * 1024);
        const uint4* g3 = (const uint4*)(ws + OFF_W3F + (size_t)f0 * 128);
        uint4* dA = (uint4*)sA1;
        uint4* dW = (uint4*)sW2;
        uint4* d3 = (uint4*)sW3f;
        dA[t] = gA[t];                 // 256 uint4
        dW[t]       = gW[t];           // 512 uint4
        dW[t + 256] = gW[t + 256];
        if (t < 64) d3[t] = g3[t];     // 64 uint4
    }
    __syncthreads();

    const short* __restrict__ a1l = sA1 + l * 8;
    const short* __restrict__ w2l = sW2 + l * 8;

    const unsigned himask = hi ? 0x3F800000u : 0u;   // bf16(1.0) @ k15 for hi lanes
    const float onef = 1.0f;                         // loop-invariant VGPR for cvtpk
    const f32x16 zc = {};

    float2 a0t0 = {0.f, 0.f}, a1t0 = {0.f, 0.f};     // tile-0 accumulators
    float2 a0t1 = {0.f, 0.f}, a1t1 = {0.f, 0.f};     // tile-1 accumulators

    auto epi = [&](const f32x16& d2, const float* __restrict__ wf,
                   float2& e0, float2& e1) {
        float r[16];
#pragma unroll
        for (int i = 0; i < 16; ++i) r[i] = fmaxf(d2[i], 0.f);
        const float4 w0  = ((const float4*)wf)[0];
        const float4 w1  = ((const float4*)wf)[1];
        const float4 w2_ = ((const float4*)wf)[2];
        const float4 w3_ = ((const float4*)wf)[3];
        e0 = pkfma(float2{r[0],  r[1]},  float2{w0.x,  w0.y},  e0);
        e1 = pkfma(float2{r[2],  r[3]},  float2{w0.z,  w0.w},  e1);
        e0 = pkfma(float2{r[4],  r[5]},  float2{w1.x,  w1.y},  e0);
        e1 = pkfma(float2{r[6],  r[7]},  float2{w1.z,  w1.w},  e1);
        e0 = pkfma(float2{r[8],  r[9]},  float2{w2_.x, w2_.y}, e0);
        e1 = pkfma(float2{r[10], r[11]}, float2{w2_.z, w2_.w}, e1);
        e0 = pkfma(float2{r[12], r[13]}, float2{w3_.x, w3_.y}, e0);
        e1 = pkfma(float2{r[14], r[15]}, float2{w3_.z, w3_.w}, e1);
    };

    // one pair (features 2pp, 2pp+1) for BOTH row tiles; fragments shared
    auto pair_body = [&](int pp,
                         float x0A, float x1A, float x2A, float x0B, float x1B, float x2B,
                         float z0A, float z1A, float z2A, float z0B, float z1B, float z2B) {
        const short8 A1  = *reinterpret_cast<const short8*>(a1l + (size_t)pp * 512);
        const short8 W2A = *reinterpret_cast<const short8*>(w2l + (size_t)(2 * pp) * 512);
        const short8 W2B = *reinterpret_cast<const short8*>(w2l + (size_t)(2 * pp + 1) * 512);

        union { unsigned u[4]; short8 s; } B0, B1v;
        B0.u[0]  = cvtpk(x0A, x1A);  B0.u[1]  = cvtpk(x2A, onef);
        B0.u[2]  = cvtpk(x0B, x1B);  B0.u[3]  = cvtpk(x2B, onef);
        B1v.u[0] = cvtpk(z0A, z1A);  B1v.u[1] = cvtpk(z2A, onef);
        B1v.u[2] = cvtpk(z0B, z1B);  B1v.u[3] = cvtpk(z2B, onef);

        // layer 1 for both tiles (independent MFMAs issue back-to-back)
        const f32x16 d1_0 = __builtin_amdgcn_mfma_f32_32x32x16_bf16(A1, B0.s,  zc, 0, 0, 0);
        const f32x16 d1_1 = __builtin_amdgcn_mfma_f32_32x32x16_bf16(A1, B1v.s, zc, 0, 0, 0);

        union { unsigned u[4]; short8 s; } PA0, PB0, PA1, PB1;
#pragma unroll
        for (int i = 0; i < 4; ++i) {
            PA0.u[i] = cvtpk(fmaxf(d1_0[2 * i], 0.f),     fmaxf(d1_0[2 * i + 1], 0.f));
            PB0.u[i] = cvtpk(fmaxf(d1_0[8 + 2 * i], 0.f), fmaxf(d1_0[8 + 2 * i + 1], 0.f));
            PA1.u[i] = cvtpk(fmaxf(d1_1[2 * i], 0.f),     fmaxf(d1_1[2 * i + 1], 0.f));
            PB1.u[i] = cvtpk(fmaxf(d1_1[8 + 2 * i], 0.f), fmaxf(d1_1[8 + 2 * i + 1], 0.f));
        }
        PA0.u[3] |= himask;  PB0.u[3] |= himask;
        PA1.u[3] |= himask;  PB1.u[3] |= himask;

        const float* wfA = sW3f + (2 * pp) * 32 + hi * 16;
        const float* wfB = sW3f + (2 * pp + 1) * 32 + hi * 16;

        // layer 2 transposed, 4 MFMAs sharing the two W2 fragments
        const f32x16 dA0 = __builtin_amdgcn_mfma_f32_32x32x16_bf16(W2A, PA0.s, zc, 0, 0, 0);
        epi(dA0, wfA, a0t0, a1t0);
        const f32x16 dA1 = __builtin_amdgcn_mfma_f32_32x32x16_bf16(W2A, PA1.s, zc, 0, 0, 0);
        epi(dA1, wfA, a0t1, a1t1);
        const f32x16 dB0 = __builtin_amdgcn_mfma_f32_32x32x16_bf16(W2B, PB0.s, zc, 0, 0, 0);
        epi(dB0, wfB, a0t0, a1t0);
        const f32x16 dB1 = __builtin_amdgcn_mfma_f32_32x32x16_bf16(W2B, PB1.s, zc, 0, 0, 0);
        epi(dB1, wfB, a0t1, a1t1);
    };

    // batch 0: features f0..f0+3 (pairs 0,1) for both tiles
    {
        const float4 c0 = ya4[0], c1 = ya4[1], c2 = ya4[2];
        const float4 d0 = yb4[0], d1 = yb4[1], d2 = yb4[2];
        pair_body(0, c0.x, c0.y, c0.z,  c0.w, c1.x, c1.y,
                     d0.x, d0.y, d0.z,  d0.w, d1.x, d1.y);
        pair_body(1, c1.z, c1.w, c2.x,  c2.y, c2.z, c2.w,
                     d1.z, d1.w, d2.x,  d2.y, d2.z, d2.w);
    }
    // batch 1: features f0+4..f0+7 (pairs 2,3)
    {
        const float4 c0 = ya4[3], c1 = ya4[4], c2 = ya4[5];
        const float4 d0 = yb4[3], d1 = yb4[4], d2 = yb4[5];
        pair_body(2, c0.x, c0.y, c0.z,  c0.w, c1.x, c1.y,
                     d0.x, d0.y, d0.z,  d0.w, d1.x, d1.y);
        pair_body(3, c1.z, c1.w, c2.x,  c2.y, c2.z, c2.w,
                     d1.z, d1.w, d2.x,  d2.y, d2.z, d2.w);
    }

    // ---- combine accumulators + the two e-halves (lanes l and l^32 same brow) ----
    float p0s = (a0t0.x + a1t0.x) + (a0t0.y + a1t0.y);
    float p1s = (a0t1.x + a1t1.x) + (a0t1.y + a1t1.y);
    p0s += __shfl_xor(p0s, 32);
    p1s += __shfl_xor(p1s, 32);
    if (hi == 0) {
        atomicAdd(&out[r0 + ln], p0s);
        atomicAdd(&out[r1 + ln], p1s);
    }
}

extern "C" void kernel_launch(void* const* d_in, const int* in_sizes, int n_in,
                              void* d_out, int out_size, void* d_ws, size_t ws_size,
                              hipStream_t stream) {
    const float* y  = (const float*)d_in[0];
    const float* W1 = (const float*)d_in[1];
    const float* b1 = (const float*)d_in[2];
    const float* W2 = (const float*)d_in[3];
    const float* b2 = (const float*)d_in[4];
    const float* W3 = (const float*)d_in[5];
    const float* b3 = (const float*)d_in[6];
    float* out = (float*)d_out;

    nn_prep<<<dim3(NF), dim3(64), 0, stream>>>(W1, b1, W2, b2, W3, (char*)d_ws);
    nn_init<<<dim3((NB + 255) / 256), dim3(256), 0, stream>>>(out, b3);
    nn_main<<<dim3(NB / RPB, FSPLIT), dim3(BT), 0, stream>>>(
        y, (const char*)d_ws, out);
}

// Round 17
// 42.209 us; speedup vs baseline: 1.0166x; 1.0166x over previous
//
#include <hip/hip_runtime.h>
#include <hip/hip_bf16.h>

// Problem constants
#define NF  200
#define DIN 3
#define NH  15
#define NE  30
#define NB  32768

typedef __attribute__((ext_vector_type(8)))  short short8;
typedef __attribute__((ext_vector_type(16))) float f32x16;

constexpr int FSPLIT = 25;           // feature split across grid.y
constexpr int FPW    = NF / FSPLIT;  // 8 features per block-slice -> 4 pairs
constexpr int PAIRS  = FPW / 2;      // 4
constexpr int BT     = 256;          // threads per block (4 waves)
constexpr int RPW    = 32;           // rows per wave (one 32x32 MFMA tile)
constexpr int RPB    = 4 * RPW;      // 128 rows per block -> grid.x = 256

// ws layout:
// A1P : [100][64][8 bf16] pair-packed layer-1 A-frag            @ 0       (102400 B)
// W2Q : [200][64][8 bf16] layer-2 W2 fragment (lane=e, k=perm'd h, b2@k15)
//                                                                @ 102400  (204800 B)
// W3F : [200][2][16] f32  W3 in D-fragment order                @ 307200  (25600 B)
constexpr size_t OFF_A1P = 0;
constexpr size_t OFF_W2Q = 102400;
constexpr size_t OFF_W3F = 307200;

__device__ __forceinline__ unsigned f2bfu(float x) {
    __hip_bfloat16 h = __float2bfloat16(x);
    unsigned short u; __builtin_memcpy(&u, &h, 2); return (unsigned)u;
}

// HW packed convert: lo -> D[15:0], hi -> D[31:16], RNE (same as __float2bfloat16)
__device__ __forceinline__ unsigned cvtpk(float lo, float hi) {
    unsigned r;
    asm("v_cvt_pk_bf16_f32 %0, %1, %2" : "=v"(r) : "v"(lo), "v"(hi));
    return r;
}

// VOP3P packed fp32 FMA: d = a*b + c on both halves (2 MACs / instr)
__device__ __forceinline__ float2 pkfma(float2 a, float2 b, float2 c) {
    float2 d;
    asm("v_pk_fma_f32 %0, %1, %2, %3" : "=v"(d) : "v"(a), "v"(b), "v"(c));
    return d;
}

__global__ void nn_init(float* __restrict__ out, const float* __restrict__ b3) {
    int i = blockIdx.x * 256 + threadIdx.x;
    if (i < NB) out[i] = b3[0];
}

__global__ void nn_prep(const float* __restrict__ W1, const float* __restrict__ b1,
                        const float* __restrict__ W2, const float* __restrict__ b2,
                        const float* __restrict__ W3, char* __restrict__ ws) {
    const int f = blockIdx.x;
    const int t = threadIdx.x;      // 64
    const int x = t & 31, hi = t >> 5;
    unsigned short* A1p = (unsigned short*)(ws + OFF_A1P);
    unsigned short* W2q = (unsigned short*)(ws + OFF_W2Q);
    float*          w3f = (float*)(ws + OFF_W3F);

    // ---- W2 fragment (lane=e, k-slots=perm'd h); h==15 slot carries b2 ----
    {
        unsigned short* d = W2q + ((size_t)f * 64 + t) * 8;
#pragma unroll
        for (int j = 0; j < 8; ++j) {
            const int h = (j & 3) + 8 * (j >> 2) + 4 * hi;   // 0..15
            float v = 0.f;
            if (x < NE) v = (h < NH) ? W2[((size_t)f * NH + h) * NE + x]
                                     : b2[f * NE + x];       // h==15
            d[j] = (unsigned short)f2bfu(v);
        }
    }
    // ---- W3 in D-fragment order: W3F[f][hi][r] = W3[e=crow(r,hi)] (e>=30 -> 0)
    if (t < 32) {
        const int hh = t >> 4, r = t & 15;
        const int e = (r & 3) + 8 * (r >> 2) + 4 * hh;
        w3f[(size_t)f * 32 + t] = (e < NE) ? W3[f * NE + e] : 0.f;
    }

    // ---- pair-packed layer-1 A fragment (even f writes pair f/2) ----
    if ((f & 1) == 0) {
        unsigned short* a = A1p + ((size_t)(f >> 1) * 64 + t) * 8;
#pragma unroll
        for (int j = 0; j < 8; ++j) {
            float v = 0.f;
            if (hi == 0) {
                if (x < 16) {                    // feature f, h = x, k0-3
                    if (x < NH) {
                        if (j < 3)       v = W1[((size_t)f * DIN + j) * NH + x];
                        else if (j == 3) v = b1[f * NH + x];
                    }
                } else {                          // feature f+1, h = x-16, k4-7
                    const int h = x - 16;
                    if (h < NH) {
                        if (j >= 4 && j < 7) v = W1[((size_t)(f + 1) * DIN + (j - 4)) * NH + h];
                        else if (j == 7)     v = b1[(f + 1) * NH + h];
                    }
                }
            }
            a[j] = (unsigned short)f2bfu(v);
        }
    }
}

__global__ __launch_bounds__(BT, 3)
void nn_main(const float* __restrict__ y, const char* __restrict__ ws,
             float* __restrict__ out) {
    // LDS-staged per-block weight slice -- 13.3 KB total
    __shared__ __align__(16) short sA1[PAIRS * 512];   //  4096 B = 256 uint4
    __shared__ __align__(16) short sW2[FPW * 512];     //  8192 B = 512 uint4
    __shared__ __align__(16) float sW3f[FPW * 32];     //  1024 B =  64 uint4

    const int t  = threadIdx.x;
    const int w  = t >> 6;
    const int l  = t & 63;
    const int ln = l & 31;
    const int hi = l >> 5;
    const int r0 = blockIdx.x * RPB + w * RPW;
    const int f0 = blockIdx.y * FPW;
    const int p0 = f0 >> 1;

    // ---- issue ALL y loads first (independent of LDS staging / barrier) ----
    // f0*3 floats = 96B*by -> 16B-aligned float4 base; 6 x float4 = 8 features
    const float4* __restrict__ yp4 = reinterpret_cast<const float4*>(
        y + (size_t)(r0 + ln) * (NF * DIN) + (size_t)f0 * DIN);
    const float4 c0 = yp4[0], c1 = yp4[1], c2 = yp4[2];
    const float4 c3 = yp4[3], c4 = yp4[4], c5 = yp4[5];

    // ---- stage weights global -> LDS (coalesced uint4 copies, BT=256) ----
    {
        const uint4* gA = (const uint4*)(ws + OFF_A1P + (size_t)p0 * 1024);
        const uint4* gW = (const uint4*)(ws + OFF_W2Q + (size_t)f0 * 1024);
        const uint4* g3 = (const uint4*)(ws + OFF_W3F + (size_t)f0 * 128);
        uint4* dA = (uint4*)sA1;
        uint4* dW = (uint4*)sW2;
        uint4* d3 = (uint4*)sW3f;
        dA[t] = gA[t];                 // 256 uint4
        dW[t]       = gW[t];           // 512 uint4
        dW[t + 256] = gW[t + 256];
        if (t < 64) d3[t] = g3[t];     // 64 uint4
    }
    __syncthreads();

    const short* __restrict__ a1l = sA1 + l * 8;
    const short* __restrict__ w2l = sW2 + l * 8;

    const unsigned himask = hi ? 0x3F800000u : 0u;   // bf16(1.0) @ k15 for hi lanes
    const float onef = 1.0f;                         // loop-invariant VGPR for cvtpk
    const f32x16 zc = {};

    float2 acc0 = {0.f, 0.f};
    float2 acc1 = {0.f, 0.f};

    auto epilogue = [&](const f32x16& d2, const float* __restrict__ wf) {
        float r[16];
#pragma unroll
        for (int i = 0; i < 16; ++i) r[i] = fmaxf(d2[i], 0.f);
        const float4 w0  = ((const float4*)wf)[0];
        const float4 w1  = ((const float4*)wf)[1];
        const float4 w2_ = ((const float4*)wf)[2];
        const float4 w3_ = ((const float4*)wf)[3];
        acc0 = pkfma(float2{r[0],  r[1]},  float2{w0.x,  w0.y},  acc0);
        acc1 = pkfma(float2{r[2],  r[3]},  float2{w0.z,  w0.w},  acc1);
        acc0 = pkfma(float2{r[4],  r[5]},  float2{w1.x,  w1.y},  acc0);
        acc1 = pkfma(float2{r[6],  r[7]},  float2{w1.z,  w1.w},  acc1);
        acc0 = pkfma(float2{r[8],  r[9]},  float2{w2_.x, w2_.y}, acc0);
        acc1 = pkfma(float2{r[10], r[11]}, float2{w2_.z, w2_.w}, acc1);
        acc0 = pkfma(float2{r[12], r[13]}, float2{w3_.x, w3_.y}, acc0);
        acc1 = pkfma(float2{r[14], r[15]}, float2{w3_.z, w3_.w}, acc1);
    };

    auto pair_body = [&](int pp, float y0A, float y1A, float y2A,
                                 float y0B, float y1B, float y2B) {
        const short8 A1  = *reinterpret_cast<const short8*>(a1l + (size_t)pp * 512);
        const short8 W2A = *reinterpret_cast<const short8*>(w2l + (size_t)(2 * pp) * 512);
        const short8 W2B = *reinterpret_cast<const short8*>(w2l + (size_t)(2 * pp + 1) * 512);

        // B1: k0-2 = y_A, k3 = 1, k4-6 = y_B, k7 = 1 (hi lanes' B garbage-OK: A rows zero)
        union { unsigned u[4]; short8 s; } B1;
        B1.u[0] = cvtpk(y0A, y1A);
        B1.u[1] = cvtpk(y2A, onef);
        B1.u[2] = cvtpk(y0B, y1B);
        B1.u[3] = cvtpk(y2B, onef);

        // layer 1: d1[h][brow] (lane = brow, regs = perm'd h)
        const f32x16 d1 = __builtin_amdgcn_mfma_f32_32x32x16_bf16(A1, B1.s, zc, 0, 0, 0);

        // pack relu(h1) as layer-2 B-operand; 1.0 @ k15 multiplies the b2 row
        union { unsigned u[4]; short8 s; } PA, PB;
#pragma unroll
        for (int i = 0; i < 4; ++i) {
            PA.u[i] = cvtpk(fmaxf(d1[2 * i], 0.f),     fmaxf(d1[2 * i + 1], 0.f));
            PB.u[i] = cvtpk(fmaxf(d1[8 + 2 * i], 0.f), fmaxf(d1[8 + 2 * i + 1], 0.f));
        }
        PA.u[3] |= himask;
        PB.u[3] |= himask;

        // layer 2 TRANSPOSED: d2t[e][brow] = mfma(W2frag, packed-h1)
        const f32x16 dA2 = __builtin_amdgcn_mfma_f32_32x32x16_bf16(W2A, PA.s, zc, 0, 0, 0);
        epilogue(dA2, sW3f + (2 * pp) * 32 + hi * 16);
        const f32x16 dB2 = __builtin_amdgcn_mfma_f32_32x32x16_bf16(W2B, PB.s, zc, 0, 0, 0);
        epilogue(dB2, sW3f + (2 * pp + 1) * 32 + hi * 16);
    };

    pair_body(0, c0.x, c0.y, c0.z,  c0.w, c1.x, c1.y);
    pair_body(1, c1.z, c1.w, c2.x,  c2.y, c2.z, c2.w);
    pair_body(2, c3.x, c3.y, c3.z,  c3.w, c4.x, c4.y);
    pair_body(3, c4.z, c4.w, c5.x,  c5.y, c5.z, c5.w);

    // ---- combine accumulators + the two e-halves (lanes l and l^32 same brow) ----
    float partial = (acc0.x + acc1.x) + (acc0.y + acc1.y);
    partial += __shfl_xor(partial, 32);
    if (hi == 0) atomicAdd(&out[r0 + ln], partial);
}

extern "C" void kernel_launch(void* const* d_in, const int* in_sizes, int n_in,
                              void* d_out, int out_size, void* d_ws, size_t ws_size,
                              hipStream_t stream) {
    const float* y  = (const float*)d_in[0];
    const float* W1 = (const float*)d_in[1];
    const float* b1 = (const float*)d_in[2];
    const float* W2 = (const float*)d_in[3];
    const float* b2 = (const float*)d_in[4];
    const float* W3 = (const float*)d_in[5];
    const float* b3 = (const float*)d_in[6];
    float* out = (float*)d_out;

    nn_prep<<<dim3(NF), dim3(64), 0, stream>>>(W1, b1, W2, b2, W3, (char*)d_ws);
    nn_init<<<dim3((NB + 255) / 256), dim3(256), 0, stream>>>(out, b3);
    nn_main<<<dim3(NB / RPB, FSPLIT), dim3(BT), 0, stream>>>(
        y, (const char*)d_ws, out);
}